// Round 3
// baseline (540.126 us; speedup 1.0000x reference)
//
#include <hip/hip_runtime.h>
#include <hip/hip_bf16.h>
#include <stdint.h>

// Problem constants
#define L_DIM 4096
#define B_DIM 32
#define H_DIM 512
#define M_DIM (L_DIM * B_DIM)  // 131072 rows of the fused GEMM
#define K_DIM H_DIM            // 512 reduction dim

typedef _Float16 half8 __attribute__((ext_vector_type(8)));
typedef __fp16 fp16x2 __attribute__((ext_vector_type(2)));  // cvt_pkrtz return type
typedef float floatx4 __attribute__((ext_vector_type(4)));

// tanh(x) = 1 - 2/(1 + e^{2x}), via hw exp2 + rcp (~1e-7 abs err, saturates correctly)
__device__ __forceinline__ float tanh_fast(float x) {
  float e = __builtin_amdgcn_exp2f(x * 2.88539008177793f);  // 2*log2(e)
  return 1.0f - 2.0f * __builtin_amdgcn_rcpf(e + 1.0f);
}

__device__ __forceinline__ half8 pack8(const float4& f0, const float4& f1) {
  const fp16x2 p0 = __builtin_amdgcn_cvt_pkrtz(f0.x, f0.y);
  const fp16x2 p1 = __builtin_amdgcn_cvt_pkrtz(f0.z, f0.w);
  const fp16x2 p2 = __builtin_amdgcn_cvt_pkrtz(f1.x, f1.y);
  const fp16x2 p3 = __builtin_amdgcn_cvt_pkrtz(f1.z, f1.w);
  struct { fp16x2 a, b, c, d; } s{p0, p1, p2, p3};
  return __builtin_bit_cast(half8, s);
}

// ---------------------------------------------------------------------------
// q_proj[b][h] = sum_i query[b][i] * W[i][h]   (fp32, exact; 32x512 output)
__global__ __launch_bounds__(128) void qproj_kernel(const float* __restrict__ query,
                                                    const float* __restrict__ W,
                                                    float* __restrict__ qp) {
  const int b = blockIdx.x;
  const int h = threadIdx.x * 4;
  const float* qrow = query + b * H_DIM;
  float4 acc = make_float4(0.f, 0.f, 0.f, 0.f);
#pragma unroll 8
  for (int i = 0; i < K_DIM; ++i) {
    const float qv = qrow[i];
    const float4 w4 = *(const float4*)(W + (size_t)i * H_DIM + h);
    acc.x += qv * w4.x; acc.y += qv * w4.y;
    acc.z += qv * w4.z; acc.w += qv * w4.w;
  }
  *(float4*)(qp + (size_t)b * H_DIM + h) = acc;
}

// ---------------------------------------------------------------------------
// Build W2: Wk (=W[512:]) fp16, packed so a lane's MFMA B-fragment is one
// contiguous 16B chunk and a wave's per-fn load is 1KB fully coalesced.
// chunk c = ((kt*32 + nc)*4 + q)*16 + l15 holds Wk[k=kt*32+q*8+j][n=nc*16+l15].
__global__ __launch_bounds__(256) void wconv_kernel(const float* __restrict__ W,
                                                    _Float16* __restrict__ W2) {
  const int t = blockIdx.x * 256 + threadIdx.x;  // [0, 32768) chunk index
  const int l15 = t & 15;
  const int q = (t >> 4) & 3;
  const int nc = (t >> 6) & 31;
  const int kt = t >> 11;
  const int n = nc * 16 + l15;
  const int kbase = H_DIM + kt * 32 + q * 8;  // Wk rows live at W[512 + k]
  half8 h;
#pragma unroll
  for (int j = 0; j < 8; ++j)
    h[j] = (_Float16)W[(size_t)(kbase + j) * H_DIM + n];
  *(half8*)(W2 + (size_t)t * 8) = h;
}

// ---------------------------------------------------------------------------
// Fused GEMM + tanh + v-dot. Block: 64 rows x 512 cols (full H: key read once).
// 4 waves; wave w owns n-slice [w*128, w*128+128). NO LDS / NO barriers in the
// K-loop: A and B fragments load global->VGPR directly (B pre-packed by wconv,
// A per-lane 32B exactly matching the mfma_16x16x32_f16 A layout
// A[m=lane&15][k=quad*8+j]). One-iteration register prefetch on A hides HBM.
__global__ __launch_bounds__(256, 2) void fused_gemm_kernel(
    const float* __restrict__ key, const _Float16* __restrict__ W2,
    const float* __restrict__ qp, const float* __restrict__ v,
    float* __restrict__ scores) {
  __shared__ float swave[256];

  const int tid = threadIdx.x;
  const int lane = tid & 63;
  const int w = tid >> 6;
  const int l15 = lane & 15;
  const int quad = lane >> 4;
  const int m0 = blockIdx.x * 64;

  // A: lane (quad,l15) reads rows m0+fm*16+l15, k = kt*32 + quad*8 .. +8
  const float* aptr[4];
#pragma unroll
  for (int fm = 0; fm < 4; ++fm)
    aptr[fm] = key + (size_t)(m0 + fm * 16 + l15) * K_DIM + quad * 8;

  // B: chunk index for (kt, fn) = (kt*32 + w*8 + fn)*64 + lane; 16B chunks
  const half8* bptr = (const half8*)W2 + (size_t)(w * 8) * 64 + lane;

  floatx4 acc[4][8];
#pragma unroll
  for (int fm = 0; fm < 4; ++fm)
#pragma unroll
    for (int fn = 0; fn < 8; ++fn) acc[fm][fn] = (floatx4)0.0f;

  // prologue: issue A(0)
  float4 ra0[4], ra1[4];
#pragma unroll
  for (int fm = 0; fm < 4; ++fm) {
    ra0[fm] = *(const float4*)(aptr[fm]);
    ra1[fm] = *(const float4*)(aptr[fm] + 4);
    aptr[fm] += 32;  // now points at kt=1 data
  }

#pragma unroll 3
  for (int kt = 0; kt < 15; ++kt) {
    // B(kt): 8 coalesced 1KB wave loads, straight into fragment regs
    half8 bv[8];
#pragma unroll
    for (int fn = 0; fn < 8; ++fn) bv[fn] = bptr[fn * 64];
    bptr += 32 * 64;
    // cvt A(kt) raw->fp16 frags (waits on loads issued last iteration)
    half8 av[4];
#pragma unroll
    for (int fm = 0; fm < 4; ++fm) av[fm] = pack8(ra0[fm], ra1[fm]);
    // prefetch A(kt+1) into the now-free raw regs
#pragma unroll
    for (int fm = 0; fm < 4; ++fm) {
      ra0[fm] = *(const float4*)(aptr[fm]);
      ra1[fm] = *(const float4*)(aptr[fm] + 4);
      aptr[fm] += 32;
    }
#pragma unroll
    for (int fm = 0; fm < 4; ++fm)
#pragma unroll
      for (int fn = 0; fn < 8; ++fn)
        acc[fm][fn] = __builtin_amdgcn_mfma_f32_16x16x32_f16(av[fm], bv[fn],
                                                             acc[fm][fn], 0, 0, 0);
  }
  {  // kt = 15, no prefetch
    half8 bv[8];
#pragma unroll
    for (int fn = 0; fn < 8; ++fn) bv[fn] = bptr[fn * 64];
    half8 av[4];
#pragma unroll
    for (int fm = 0; fm < 4; ++fm) av[fm] = pack8(ra0[fm], ra1[fm]);
#pragma unroll
    for (int fm = 0; fm < 4; ++fm)
#pragma unroll
      for (int fn = 0; fn < 8; ++fn)
        acc[fm][fn] = __builtin_amdgcn_mfma_f32_16x16x32_f16(av[fm], bv[fn],
                                                             acc[fm][fn], 0, 0, 0);
  }

  // Epilogue: score[m] = sum_n v[n] * tanh(qp[m&31][n] + kproj[m][n])
  // C/D layout: col = lane&15, row = quad*4 + reg (verified round 2: passed)
  float vv[8];
#pragma unroll
  for (int fn = 0; fn < 8; ++fn) vv[fn] = v[w * 128 + fn * 16 + l15];

#pragma unroll
  for (int fm = 0; fm < 4; ++fm) {
#pragma unroll
    for (int r = 0; r < 4; ++r) {
      const int mrow = fm * 16 + quad * 4 + r;
      const float* qrow = qp + (size_t)(mrow & 31) * H_DIM;
      float rs = 0.f;
#pragma unroll
      for (int fn = 0; fn < 8; ++fn) {
        const int n = w * 128 + fn * 16 + l15;
        const float x = qrow[n] + acc[fm][fn][r];
        rs += vv[fn] * tanh_fast(x);
      }
      rs += __shfl_xor(rs, 1);
      rs += __shfl_xor(rs, 2);
      rs += __shfl_xor(rs, 4);
      rs += __shfl_xor(rs, 8);
      if (l15 == 0) swave[w * 64 + mrow] = rs;
    }
  }
  __syncthreads();
  if (tid < 64) {
    const float s = swave[tid] + swave[64 + tid] + swave[128 + tid] + swave[192 + tid];
    const int m = m0 + tid;  // m = l*32 + b
    scores[(size_t)(m & 31) * L_DIM + (m >> 5)] = s;  // transposed: [b][l]
  }
}

// ---------------------------------------------------------------------------
// softmax over l per b; scores already [b][l]; out[b][l] — fully coalesced
__global__ __launch_bounds__(256) void softmax_kernel(const float* __restrict__ scores,
                                                      float* __restrict__ out) {
  const int b = blockIdx.x;
  const int t = threadIdx.x;
  __shared__ float red[256];
  const float* srow = scores + (size_t)b * L_DIM;
  float s[16];
#pragma unroll
  for (int i = 0; i < 16; ++i) s[i] = srow[t + i * 256];
  float mx = s[0];
#pragma unroll
  for (int i = 1; i < 16; ++i) mx = fmaxf(mx, s[i]);
  red[t] = mx;
  __syncthreads();
  for (int off = 128; off > 0; off >>= 1) {
    if (t < off) red[t] = fmaxf(red[t], red[t + off]);
    __syncthreads();
  }
  mx = red[0];
  __syncthreads();
  float sum = 0.f;
#pragma unroll
  for (int i = 0; i < 16; ++i) {
    s[i] = __builtin_amdgcn_exp2f((s[i] - mx) * 1.44269504f);
    sum += s[i];
  }
  red[t] = sum;
  __syncthreads();
  for (int off = 128; off > 0; off >>= 1) {
    if (t < off) red[t] += red[t + off];
    __syncthreads();
  }
  const float inv = 1.0f / red[0];
#pragma unroll
  for (int i = 0; i < 16; ++i) out[(size_t)b * L_DIM + t + i * 256] = s[i] * inv;
}

// ---------------------------------------------------------------------------
extern "C" void kernel_launch(void* const* d_in, const int* in_sizes, int n_in,
                              void* d_out, int out_size, void* d_ws, size_t ws_size,
                              hipStream_t stream) {
  const float* query = (const float*)d_in[0];
  const float* key   = (const float*)d_in[1];
  const float* W     = (const float*)d_in[2];
  const float* v     = (const float*)d_in[3];
  float* out = (float*)d_out;

  char* ws = (char*)d_ws;
  float* qp       = (float*)ws;                        // 32*512*4   = 64 KB
  float* scores   = (float*)(ws + 65536);              // 131072*4   = 512 KB
  _Float16* W2    = (_Float16*)(ws + 65536 + 524288);  // 512*512*2  = 512 KB

  qproj_kernel<<<32, 128, 0, stream>>>(query, W, qp);
  wconv_kernel<<<128, 256, 0, stream>>>(W, W2);
  fused_gemm_kernel<<<M_DIM / 64, 256, 0, stream>>>(key, W2, qp, v, scores);
  softmax_kernel<<<B_DIM, 256, 0, stream>>>(scores, out);
}

// Round 5
// 446.764 us; speedup vs baseline: 1.2090x; 1.2090x over previous
//
#include <hip/hip_runtime.h>
#include <hip/hip_bf16.h>
#include <stdint.h>

// Problem constants
#define L_DIM 4096
#define B_DIM 32
#define H_DIM 512
#define M_DIM (L_DIM * B_DIM)  // 131072 rows of the fused GEMM
#define K_DIM H_DIM            // 512 reduction dim

typedef _Float16 half8 __attribute__((ext_vector_type(8)));
typedef __fp16 fp16x2 __attribute__((ext_vector_type(2)));  // cvt_pkrtz return type
typedef float floatx4 __attribute__((ext_vector_type(4)));

// tanh(x) = 1 - 2/(1 + e^{2x}), via hw exp2 + rcp (~1e-7 abs err, saturates correctly)
__device__ __forceinline__ float tanh_fast(float x) {
  float e = __builtin_amdgcn_exp2f(x * 2.88539008177793f);  // 2*log2(e)
  return 1.0f - 2.0f * __builtin_amdgcn_rcpf(e + 1.0f);
}

__device__ __forceinline__ uint2 pack4(const float4& f) {
  const fp16x2 p0 = __builtin_amdgcn_cvt_pkrtz(f.x, f.y);
  const fp16x2 p1 = __builtin_amdgcn_cvt_pkrtz(f.z, f.w);
  uint2 u;
  u.x = __builtin_bit_cast(unsigned, p0);
  u.y = __builtin_bit_cast(unsigned, p1);
  return u;
}

// ---------------------------------------------------------------------------
// q_proj[b][h] = sum_i query[b][i] * W[i][h]   (fp32, exact; 32x512 output)
__global__ __launch_bounds__(128) void qproj_kernel(const float* __restrict__ query,
                                                    const float* __restrict__ W,
                                                    float* __restrict__ qp) {
  const int b = blockIdx.x;
  const int h = threadIdx.x * 4;
  const float* qrow = query + b * H_DIM;
  float4 acc = make_float4(0.f, 0.f, 0.f, 0.f);
#pragma unroll 8
  for (int i = 0; i < K_DIM; ++i) {
    const float qv = qrow[i];
    const float4 w4 = *(const float4*)(W + (size_t)i * H_DIM + h);
    acc.x += qv * w4.x; acc.y += qv * w4.y;
    acc.z += qv * w4.z; acc.w += qv * w4.w;
  }
  *(float4*)(qp + (size_t)b * H_DIM + h) = acc;
}

// ---------------------------------------------------------------------------
// Build W2: Wk (=W[512:]) fp16, packed so a lane's MFMA B-fragment is one
// contiguous 16B chunk and a wave's per-fn load is 1KB fully coalesced.
// chunk c = ((kt*32 + nc)*4 + q)*16 + l15 holds Wk[k=kt*32+q*8+j][n=nc*16+l15].
__global__ __launch_bounds__(256) void wconv_kernel(const float* __restrict__ W,
                                                    _Float16* __restrict__ W2) {
  const int t = blockIdx.x * 256 + threadIdx.x;  // [0, 32768) chunk index
  const int l15 = t & 15;
  const int q = (t >> 4) & 3;
  const int nc = (t >> 6) & 31;
  const int kt = t >> 11;
  const int n = nc * 16 + l15;
  const int kbase = H_DIM + kt * 32 + q * 8;  // Wk rows live at W[512 + k]
  half8 h;
#pragma unroll
  for (int j = 0; j < 8; ++j)
    h[j] = (_Float16)W[(size_t)(kbase + j) * H_DIM + n];
  *(half8*)(W2 + (size_t)t * 8) = h;
}

// ---------------------------------------------------------------------------
// Fused GEMM + tanh + v-dot. 64 rows x 512 cols per block (key read once).
// A: LDS double-buffer (fp16, padded stride 40), ONE barrier/iter; global A
// loads are lane-contiguous 16B (8x128B lines/wave) and prefetched 2 iters
// ahead; staging uses VGPR+ds_write so s_barrier needs no vmcnt drain --
// global loads stay in flight across it. B: global->VGPR direct (W2 packed
// per-fragment), prefetched 1 iter ahead, L2-resident.
__global__ __launch_bounds__(256, 2) void fused_gemm_kernel(
    const float* __restrict__ key, const _Float16* __restrict__ W2,
    const float* __restrict__ qp, const float* __restrict__ v,
    float* __restrict__ scores) {
  __shared__ __align__(16) _Float16 As[2][64 * 40];  // pad 32->40: frag reads ~2-way
  __shared__ float swave[256];

  const int tid = threadIdx.x;
  const int lane = tid & 63;
  const int w = tid >> 6;
  const int l15 = lane & 15;
  const int quad = lane >> 4;
  const int m0 = blockIdx.x * 64;

  // A staging: thread t loads 16B chunk (t&7) of rows (t>>3) and (t>>3)+32
  const int ar = tid >> 3;       // 0..31
  const int aseg = tid & 7;      // 16B chunk within 128B k-slice
  const float* ag0 = key + (size_t)(m0 + ar) * K_DIM + aseg * 4;
  const float* ag1 = ag0 + (size_t)32 * K_DIM;
  const int adst0 = ar * 40 + aseg * 4;          // halves
  const int adst1 = (ar + 32) * 40 + aseg * 4;

  // B: chunk index for (kt, fn) = (kt*32 + w*8 + fn)*64 + lane; 16B chunks
  const half8* bptr = (const half8*)W2 + (size_t)(w * 8) * 64 + lane;

  // fragment LDS offsets
  int aoff[4];
#pragma unroll
  for (int fm = 0; fm < 4; ++fm) aoff[fm] = (fm * 16 + l15) * 40 + quad * 8;

  floatx4 acc[4][8];
#pragma unroll
  for (int fm = 0; fm < 4; ++fm)
#pragma unroll
    for (int fn = 0; fn < 8; ++fn) acc[fm][fn] = (floatx4)0.0f;

  // prologue: A(0) -> LDS buf0; issue A(1), B(0)
  float4 ra0 = *(const float4*)(ag0);
  float4 ra1 = *(const float4*)(ag1);
  half8 bn[8];
#pragma unroll
  for (int fn = 0; fn < 8; ++fn) bn[fn] = bptr[fn * 64];
  bptr += 32 * 64;
  *(uint2*)(As[0] + adst0) = pack4(ra0);
  *(uint2*)(As[0] + adst1) = pack4(ra1);
  ra0 = *(const float4*)(ag0 + 32);
  ra1 = *(const float4*)(ag1 + 32);
  __syncthreads();

  for (int kt = 0; kt < 16; ++kt) {
    half8 bc[8];
#pragma unroll
    for (int fn = 0; fn < 8; ++fn) bc[fn] = bn[fn];
    if (kt < 15) {
      // issue B(kt+1) now, consume next iteration
#pragma unroll
      for (int fn = 0; fn < 8; ++fn) bn[fn] = bptr[fn * 64];
      bptr += 32 * 64;
    }
    // frag reads for this iteration (buf kt&1, written before last barrier)
    half8 av[4];
#pragma unroll
    for (int fm = 0; fm < 4; ++fm) av[fm] = *(const half8*)(As[kt & 1] + aoff[fm]);
    if (kt < 15) {
      // stage A(kt+1) into the other buffer (raw regs issued 2 iters ago)
      _Float16* dst = As[(kt + 1) & 1];
      *(uint2*)(dst + adst0) = pack4(ra0);
      *(uint2*)(dst + adst1) = pack4(ra1);
      if (kt < 14) {
        ra0 = *(const float4*)(ag0 + (kt + 2) * 32);
        ra1 = *(const float4*)(ag1 + (kt + 2) * 32);
      }
    }
#pragma unroll
    for (int fm = 0; fm < 4; ++fm)
#pragma unroll
      for (int fn = 0; fn < 8; ++fn)
        acc[fm][fn] = __builtin_amdgcn_mfma_f32_16x16x32_f16(av[fm], bc[fn],
                                                             acc[fm][fn], 0, 0, 0);
    __syncthreads();  // lgkmcnt only: outstanding global loads cross freely
  }

  // Epilogue: score[m] = sum_n v[n] * tanh(qp[m&31][n] + kproj[m][n])
  // C/D layout: col = lane&15, row = quad*4 + reg (verified: passes)
  float vv[8];
#pragma unroll
  for (int fn = 0; fn < 8; ++fn) vv[fn] = v[w * 128 + fn * 16 + l15];

#pragma unroll
  for (int fm = 0; fm < 4; ++fm) {
#pragma unroll
    for (int r = 0; r < 4; ++r) {
      const int mrow = fm * 16 + quad * 4 + r;
      const float* qrow = qp + (size_t)(mrow & 31) * H_DIM;
      float rs = 0.f;
#pragma unroll
      for (int fn = 0; fn < 8; ++fn) {
        const int n = w * 128 + fn * 16 + l15;
        const float x = qrow[n] + acc[fm][fn][r];
        rs += vv[fn] * tanh_fast(x);
      }
      rs += __shfl_xor(rs, 1);
      rs += __shfl_xor(rs, 2);
      rs += __shfl_xor(rs, 4);
      rs += __shfl_xor(rs, 8);
      if (l15 == 0) swave[w * 64 + mrow] = rs;
    }
  }
  __syncthreads();
  if (tid < 64) {
    const float s = swave[tid] + swave[64 + tid] + swave[128 + tid] + swave[192 + tid];
    const int m = m0 + tid;  // m = l*32 + b
    scores[(size_t)(m & 31) * L_DIM + (m >> 5)] = s;  // transposed: [b][l]
  }
}

// ---------------------------------------------------------------------------
// softmax over l per b; scores already [b][l]; out[b][l] — fully coalesced
__global__ __launch_bounds__(256) void softmax_kernel(const float* __restrict__ scores,
                                                      float* __restrict__ out) {
  const int b = blockIdx.x;
  const int t = threadIdx.x;
  __shared__ float red[256];
  const float* srow = scores + (size_t)b * L_DIM;
  float s[16];
#pragma unroll
  for (int i = 0; i < 16; ++i) s[i] = srow[t + i * 256];
  float mx = s[0];
#pragma unroll
  for (int i = 1; i < 16; ++i) mx = fmaxf(mx, s[i]);
  red[t] = mx;
  __syncthreads();
  for (int off = 128; off > 0; off >>= 1) {
    if (t < off) red[t] = fmaxf(red[t], red[t + off]);
    __syncthreads();
  }
  mx = red[0];
  __syncthreads();
  float sum = 0.f;
#pragma unroll
  for (int i = 0; i < 16; ++i) {
    s[i] = __builtin_amdgcn_exp2f((s[i] - mx) * 1.44269504f);
    sum += s[i];
  }
  red[t] = sum;
  __syncthreads();
  for (int off = 128; off > 0; off >>= 1) {
    if (t < off) red[t] += red[t + off];
    __syncthreads();
  }
  const float inv = 1.0f / red[0];
#pragma unroll
  for (int i = 0; i < 16; ++i) out[(size_t)b * L_DIM + t + i * 256] = s[i] * inv;
}

// ---------------------------------------------------------------------------
extern "C" void kernel_launch(void* const* d_in, const int* in_sizes, int n_in,
                              void* d_out, int out_size, void* d_ws, size_t ws_size,
                              hipStream_t stream) {
  const float* query = (const float*)d_in[0];
  const float* key   = (const float*)d_in[1];
  const float* W     = (const float*)d_in[2];
  const float* v     = (const float*)d_in[3];
  float* out = (float*)d_out;

  char* ws = (char*)d_ws;
  float* qp       = (float*)ws;                        // 32*512*4   = 64 KB
  float* scores   = (float*)(ws + 65536);              // 131072*4   = 512 KB
  _Float16* W2    = (_Float16*)(ws + 65536 + 524288);  // 512*512*2  = 512 KB

  qproj_kernel<<<32, 128, 0, stream>>>(query, W, qp);
  wconv_kernel<<<128, 256, 0, stream>>>(W, W2);
  fused_gemm_kernel<<<M_DIM / 64, 256, 0, stream>>>(key, W2, qp, v, scores);
  softmax_kernel<<<B_DIM, 256, 0, stream>>>(scores, out);
}